// Round 11
// baseline (284.200 us; speedup 1.0000x reference)
//
#include <hip/hip_runtime.h>
#include <math.h>

typedef unsigned short u16;
typedef unsigned int u32;
typedef short bf16x8 __attribute__((ext_vector_type(8)));
typedef float f32x4 __attribute__((ext_vector_type(4)));
typedef _Float16 f16x4 __attribute__((ext_vector_type(4)));

#define TT 5
#define HEADS 6
#define HD 32
#define DIM 192
#define NWIN 320              // tokens per window = T*8*8
#define LTOK (TT*64*64)       // 20480
#define BATCH 2
#define MROWS (BATCH*LTOK)    // 40960
#define QSCALE 0.17677669529663687f   // 1/sqrt(32)
#define LOG2E 1.4426950408889634f
#define QSCALE2 (QSCALE * LOG2E)
#define MASK2 (-100.0f * LOG2E)       // -144.2695: 2^x -> 0

__device__ __forceinline__ u16 f2bf(float f) {
    u32 u = __float_as_uint(f);
    u32 r = (u + 0x7FFFu + ((u >> 16) & 1u)) >> 16;
    return (u16)r;
}
__device__ __forceinline__ float bflo(u32 u) { return __uint_as_float(u << 16); }
__device__ __forceinline__ float bfhi(u32 u) { return __uint_as_float(u & 0xFFFF0000u); }
__device__ __forceinline__ u32 pkh(float a, float b) {
    auto h = __builtin_amdgcn_cvt_pkrtz(a, b);
    return __builtin_bit_cast(u32, h);
}
#if __has_builtin(__builtin_amdgcn_exp2f)
__device__ __forceinline__ float ex2(float x) { return __builtin_amdgcn_exp2f(x); }
#else
__device__ __forceinline__ float ex2(float x) {
    float r; asm("v_exp_f32 %0, %1" : "=v"(r) : "v"(x)); return r;
}
#endif

// ------- weight conversion: qkv/proj/fc1 -> bf16, fc2 -> f16 --------------
__global__ __launch_bounds__(256) void cvt4_kernel(
    const float* __restrict__ a, const float* __restrict__ b,
    const float* __restrict__ c, const float* __restrict__ d,
    u16* __restrict__ oa, u16* __restrict__ ob,
    u16* __restrict__ oc, u16* __restrict__ od)
{
    int i = blockIdx.x * 256 + threadIdx.x;
    if (i < 110592)       oa[i]          = f2bf(a[i]);            // qkv_w 3*DIM*DIM
    else if (i < 147456)  ob[i - 110592] = f2bf(b[i - 110592]);   // proj_w DIM*DIM
    else if (i < 294912)  oc[i - 147456] = f2bf(c[i - 147456]);   // fc1_w 4*DIM*DIM
    else {
        _Float16 h = (_Float16)d[i - 294912];                     // fc2_w -> f16
        od[i - 294912] = __builtin_bit_cast(u16, h);
    }
}

// ---------------- LayerNorm: one wave per token, bf16 output --------------
__global__ __launch_bounds__(256) void ln_kernel(
    const float* __restrict__ x, const float* __restrict__ g,
    const float* __restrict__ b, u16* __restrict__ out)
{
    int tok  = blockIdx.x * 4 + (threadIdx.x >> 6);
    int lane = threadIdx.x & 63;
    const float* xr = x + (size_t)tok * DIM;
    float v0 = xr[lane], v1 = xr[lane + 64], v2 = xr[lane + 128];
    float s = v0 + v1 + v2;
    #pragma unroll
    for (int off = 32; off; off >>= 1) s += __shfl_xor(s, off, 64);
    float mu = s * (1.0f / 192.0f);
    float d0 = v0 - mu, d1 = v1 - mu, d2 = v2 - mu;
    float vs = d0 * d0 + d1 * d1 + d2 * d2;
    #pragma unroll
    for (int off = 32; off; off >>= 1) vs += __shfl_xor(vs, off, 64);
    float rstd = rsqrtf(vs * (1.0f / 192.0f) + 1e-5f);
    u16* orow = out + (size_t)tok * DIM;
    orow[lane]       = f2bf(d0 * rstd * g[lane]       + b[lane]);
    orow[lane + 64]  = f2bf(d1 * rstd * g[lane + 64]  + b[lane + 64]);
    orow[lane + 128] = f2bf(d2 * rstd * g[lane + 128] + b[lane + 128]);
}

// ---------------- bf16 MFMA GEMM: C = A(MxK) @ W(NxK)^T + bias ------------
// r4 structure (single-buffer staged loop + XCD swizzle). BM=64 for proj
// (grid fill); qkv keeps 128. History: r5 dbuf / r7 direct-A / r8 hoist all
// regressed -- do not revisit.
template<int EPI, int BM>
__global__ __launch_bounds__(256) void mfma_gemm(
    const u16* __restrict__ A, const u16* __restrict__ W,
    const float* __restrict__ bias, void* __restrict__ outp,
    const float* __restrict__ xin, int N, int K)
{
    constexpr int WR = BM / 64;     // 16-row tiles per wave
    constexpr int NA = BM / 32;     // A-stage chunks per K-step
    __shared__ u16 As[BM * 64];
    __shared__ u16 Bs[64 * 64];
    const int tid  = threadIdx.x;
    const int lane = tid & 63, wv = tid >> 6;
    const int ln16 = lane & 15, quad = lane >> 4;

    const int flat  = blockIdx.y * gridDim.x + blockIdx.x;
    const int cpx   = (gridDim.x * gridDim.y) >> 3;
    const int nf    = (flat & 7) * cpx + (flat >> 3);
    const int bn    = nf % gridDim.x;
    const int bm    = nf / gridDim.x;

    const int srow = lane >> 3;
    const int sxor = (lane & 7) ^ srow;
    const int acol = sxor * 8;

    f32x4 acc[WR][4] = {};

    for (int k0 = 0; k0 < K; k0 += 64) {
        __syncthreads();
        #pragma unroll
        for (int a = 0; a < NA; ++a) {
            const u16* g = A + (size_t)(bm * BM + a * 32 + wv * 8 + srow) * K + k0 + acol;
            __builtin_amdgcn_global_load_lds(
                (const __attribute__((address_space(1))) u32*)g,
                (__attribute__((address_space(3))) u32*)((char*)As + a * 4096 + wv * 1024),
                16, 0, 0);
        }
        #pragma unroll
        for (int bb = 0; bb < 2; ++bb) {
            const u16* g = W + (size_t)(bn * 64 + bb * 32 + wv * 8 + srow) * K + k0 + acol;
            __builtin_amdgcn_global_load_lds(
                (const __attribute__((address_space(1))) u32*)g,
                (__attribute__((address_space(3))) u32*)((char*)Bs + bb * 4096 + wv * 1024),
                16, 0, 0);
        }
        __syncthreads();
        #pragma unroll
        for (int s = 0; s < 2; ++s) {
            bf16x8 af[WR], bf[4];
            #pragma unroll
            for (int i = 0; i < WR; ++i) {
                int r = wv * (16 * WR) + i * 16 + ln16;
                int slot = (s * 4 + quad) ^ (r & 7);
                af[i] = *(const bf16x8*)((const char*)As + r * 128 + slot * 16);
            }
            #pragma unroll
            for (int j = 0; j < 4; ++j) {
                int r = j * 16 + ln16;
                int slot = (s * 4 + quad) ^ (r & 7);
                bf[j] = *(const bf16x8*)((const char*)Bs + r * 128 + slot * 16);
            }
            #pragma unroll
            for (int i = 0; i < WR; ++i)
                #pragma unroll
                for (int j = 0; j < 4; ++j)
                    acc[i][j] = __builtin_amdgcn_mfma_f32_16x16x32_bf16(
                        af[i], bf[j], acc[i][j], 0, 0, 0);
        }
    }

    #pragma unroll
    for (int i = 0; i < WR; ++i) {
        int gr0 = bm * BM + wv * (16 * WR) + i * 16 + quad * 4;
        #pragma unroll
        for (int j = 0; j < 4; ++j) {
            int gc = bn * 64 + j * 16 + ln16;
            float bv = bias[gc];
            #pragma unroll
            for (int rr = 0; rr < 4; ++rr) {
                int gr = gr0 + rr;
                float val = acc[i][j][rr] + bv;
                if (EPI == 0) {
                    ((u16*)outp)[(size_t)gr * N + gc] = f2bf(val);
                } else if (EPI == 2) {
                    int b_ = gr / NWIN, n = gr - b_ * NWIN;
                    int b = b_ >> 6, hb = (b_ >> 3) & 7, wb = b_ & 7;
                    int t = n >> 6, hi = (n >> 3) & 7, wj = n & 7;
                    int hs = (hb * 8 + hi + 4) & 63;
                    int wsrc = (wb * 8 + wj + 4) & 63;
                    size_t dst = ((size_t)b * LTOK + t * 4096 + hs * 64 + wsrc) * DIM + gc;
                    ((float*)outp)[dst] = xin[dst] + val;
                }
            }
        }
    }
}

// ------------- fused MLP: out += fc2( gelu( ln2h @ fc1^T + b1 ) )^T... ----
// One block = 64 token rows; 4 waves x 16 rows each. 12 chunks over fc1's
// 768 outputs. Per chunk: stage w1 chunk (bf16, r4 slot-swizzle) + w2 chunk
// (f16, same swizzle) into LDS; fc1 computed TRANSPOSED g^T[kc][m] =
// mfma(A=w1 rows kc, B=h rows m) so each lane ends holding
// g[m=ln16][k=quad*4+rr] -- exactly the A-operand layout of
// mfma_f32_16x16x16f16 (same P^T chaining trick the attn kernel verifies).
// gelu+bias+cvt_pkrtz pack, then 48 f16-MFMAs accumulate acc2[12] (n2-tiles).
// g never touches HBM: kills the 126MB fc1_buf round-trip.
// LDS 51KB (<64KB workgroup cap) -> 3 blocks/CU. h kept in 24 VGPRs.
__global__ __launch_bounds__(256) void fused_mlp(
    const u16* __restrict__ h,       // ln2 output, bf16 [MROWS][192]
    const u16* __restrict__ w1,      // fc1_w bf16 [768][192]
    const u16* __restrict__ w2f,     // fc2_w f16  [192][768]
    const float* __restrict__ b1,    // fc1_b [768]
    const float* __restrict__ b2,    // fc2_b [192]
    float* __restrict__ out)         // residual accum [MROWS][192]
{
    __shared__ u16 W1s[3 * 4096];    // [c][64 kc][64 k] slot-swizzled, 24KB
    __shared__ u16 W2s[12288];       // [192 n2][64 k] f16 slot-swizzled, 24KB
    __shared__ float B1s[768];       // 3KB

    const int tid  = threadIdx.x;
    const int lane = tid & 63, wv = tid >> 6;
    const int ln16 = lane & 15, quad = lane >> 4;
    const int srow = lane >> 3;
    const int acol = ((lane & 7) ^ srow) * 8;

    // XCD-chunked bijective remap, grid 640 (%8==0)
    const int flat = blockIdx.x;
    const int bm   = (flat & 7) * (gridDim.x >> 3) + (flat >> 3);

    // b1 -> LDS
    B1s[tid]       = b1[tid];
    if (tid < 256) { B1s[tid + 256] = b1[tid + 256]; B1s[tid + 512] = b1[tid + 512]; }

    // h panel -> registers: lane's m-row = bm*64 + wv*16 + ln16, 6x bf16x8
    const u16* hrow = h + (size_t)(bm * 64 + wv * 16 + ln16) * DIM + quad * 8;
    bf16x8 hf[3][2];
    #pragma unroll
    for (int c = 0; c < 3; ++c)
        #pragma unroll
        for (int s = 0; s < 2; ++s)
            hf[c][s] = *(const bf16x8*)(hrow + c * 64 + s * 32);

    f32x4 acc2[12] = {};

    #pragma unroll 1
    for (int nc = 0; nc < 12; ++nc) {
        __syncthreads();   // prior chunk's LDS reads complete before overwrite
        // stage w1 chunk: rows kc = nc*64..+64, all 192 k (3 sub-chunks)
        #pragma unroll
        for (int c = 0; c < 3; ++c)
            #pragma unroll
            for (int bb = 0; bb < 2; ++bb) {
                const u16* g = w1 + (size_t)(nc * 64 + bb * 32 + wv * 8 + srow) * DIM
                               + c * 64 + acol;
                __builtin_amdgcn_global_load_lds(
                    (const __attribute__((address_space(1))) u32*)g,
                    (__attribute__((address_space(3))) u32*)
                        ((char*)W1s + c * 8192 + bb * 4096 + wv * 1024),
                    16, 0, 0);
            }
        // stage w2 chunk: rows n2 = 0..191, cols k = nc*64..+64 (f16)
        #pragma unroll
        for (int bb = 0; bb < 6; ++bb) {
            const u16* g = w2f + (size_t)(bb * 32 + wv * 8 + srow) * 768
                           + nc * 64 + acol;
            __builtin_amdgcn_global_load_lds(
                (const __attribute__((address_space(1))) u32*)g,
                (__attribute__((address_space(3))) u32*)
                    ((char*)W2s + bb * 4096 + wv * 1024),
                16, 0, 0);
        }
        __syncthreads();

        // ---- fc1 chunk, transposed: acc1[kt] = g^T[kc-tile kt][m=ln16] ----
        f32x4 acc1[4] = {};
        #pragma unroll
        for (int c = 0; c < 3; ++c) {
            #pragma unroll
            for (int s = 0; s < 2; ++s) {
                #pragma unroll
                for (int kt = 0; kt < 4; ++kt) {
                    int rw = kt * 16 + ln16;
                    int slot = (s * 4 + quad) ^ (rw & 7);
                    bf16x8 wa = *(const bf16x8*)((const char*)W1s + c * 8192 + rw * 128 + slot * 16);
                    acc1[kt] = __builtin_amdgcn_mfma_f32_16x16x32_bf16(
                        wa, hf[c][s], acc1[kt], 0, 0, 0);
                }
            }
        }

        // ---- bias + gelu + pack to f16 A-fragments -----------------------
        f16x4 pf[4];
        #pragma unroll
        for (int kt = 0; kt < 4; ++kt) {
            const float* bp = B1s + nc * 64 + kt * 16 + quad * 4;
            float gv[4];
            #pragma unroll
            for (int rr = 0; rr < 4; ++rr) {
                float v = acc1[kt][rr] + bp[rr];
                gv[rr] = v * 0.5f * (1.0f + erff(v * 0.70710678118654752f));
            }
            uint2 pk = { pkh(gv[0], gv[1]), pkh(gv[2], gv[3]) };
            pf[kt] = __builtin_bit_cast(f16x4, pk);
        }

        // ---- fc2 partial: acc2[nt] += g-frag x w2-frag -------------------
        #pragma unroll
        for (int kt = 0; kt < 4; ++kt) {
            #pragma unroll
            for (int nt = 0; nt < 12; ++nt) {
                int rn = nt * 16 + ln16;
                int slot = (kt * 2 + (quad >> 1)) ^ (rn & 7);
                f16x4 wb = *(const f16x4*)((const char*)W2s + rn * 128 + slot * 16 + (quad & 1) * 8);
                acc2[nt] = __builtin_amdgcn_mfma_f32_16x16x16f16(
                    pf[kt], wb, acc2[nt], 0, 0, 0);
            }
        }
    }

    // ---- epilogue: out[m][n2] += acc2 + b2 -------------------------------
    #pragma unroll
    for (int nt = 0; nt < 12; ++nt) {
        int gc = nt * 16 + ln16;
        float bv = b2[gc];
        int gr0 = bm * 64 + wv * 16 + quad * 4;
        #pragma unroll
        for (int rr = 0; rr < 4; ++rr)
            out[(size_t)(gr0 + rr) * DIM + gc] += acc2[nt][rr] + bv;
    }
}

// ---------------- MFMA flash attention: block = (window, head) ------------
// r4 version verbatim (41.6us, VGPR=60, static-max exp2 softmax,
// window-order store). VGPR must stay <= 64 (m69 cliff).
__global__ __launch_bounds__(320) void attn_kernel(
    const u16* __restrict__ qkv, const float* __restrict__ table,
    u16* __restrict__ attout)
{
    const int head = blockIdx.x % HEADS;
    const int b_   = blockIdx.x / HEADS;
    const int b = b_ >> 6, hb = (b_ >> 3) & 7, wb = b_ & 7;
    const int tid = threadIdx.x;
    const int lane = tid & 63, wv = tid >> 6;
    const int ln16 = lane & 15, quad = lane >> 4;

    __shared__ u16 Ks[320 * 40];     // bf16, row pad 40 (16B-aligned rows)
    __shared__ u16 Vt[32 * 328];     // f16 transposed, row pad 328
    __shared__ u16 meta[320];        // off | (region<<8) per key token
    __shared__ float tbl[188];       // bias table pre-scaled by log2(e)

    {
        int n = tid;
        int t1 = n >> 6, r1 = (n >> 3) & 7, c1 = n & 7;
        int h1 = hb * 8 + r1, w1 = wb * 8 + c1;
        int l1 = t1 * 4096 + ((h1 + 4) & 63) * 64 + ((w1 + 4) & 63);
        const u16* src = qkv + ((size_t)b * LTOK + l1) * (3 * DIM) + head * HD;
        const uint4* k4 = (const uint4*)(src + DIM);
        #pragma unroll
        for (int i = 0; i < 4; ++i)
            *(uint4*)(Ks + n * 40 + i * 8) = k4[i];
        const uint4* v4 = (const uint4*)(src + 2 * DIM);
        #pragma unroll
        for (int i = 0; i < 4; ++i) {
            uint4 u = v4[i];
            u32 ws[4] = {u.x, u.y, u.z, u.w};
            #pragma unroll
            for (int j = 0; j < 4; ++j) {
                u32 hb2 = pkh(bflo(ws[j]), bfhi(ws[j]));
                int d = i * 8 + j * 2;
                Vt[d * 328 + n]       = (u16)(hb2 & 0xFFFF);
                Vt[(d + 1) * 328 + n] = (u16)(hb2 >> 16);
            }
        }
        int off = (7 - t1) * 15 + 7 - r1 - c1;
        int rh = h1 < 56 ? 0 : (h1 < 60 ? 1 : 2);
        int rw = w1 < 56 ? 0 : (w1 < 60 ? 1 : 2);
        meta[n] = (u16)(off | ((rh * 3 + rw) << 8));
        if (n < 187) tbl[n] = table[n * HEADS + head] * LOG2E;
    }

    bf16x8 qf[4];
    int basen[4], myreg[4];
    #pragma unroll
    for (int qt = 0; qt < 4; ++qt) {
        int nq = wv * 64 + qt * 16 + ln16;
        int t1 = nq >> 6, r1 = (nq >> 3) & 7, c1 = nq & 7;
        int h1 = hb * 8 + r1, w1 = wb * 8 + c1;
        int l1 = t1 * 4096 + ((h1 + 4) & 63) * 64 + ((w1 + 4) & 63);
        qf[qt] = *(const bf16x8*)(qkv + ((size_t)b * LTOK + l1) * (3 * DIM)
                                  + head * HD + quad * 8);
        basen[qt] = t1 * 15 + r1 + c1;
        int rh = h1 < 56 ? 0 : (h1 < 60 ? 1 : 2);
        int rw = w1 < 56 ? 0 : (w1 < 60 ? 1 : 2);
        myreg[qt] = rh * 3 + rw;
    }

    __syncthreads();

    f32x4 o[4][2] = {};
    float l_[4] = {};
    const f32x4 zero = {};

    #pragma unroll 1
    for (int c = 0; c < 10; ++c) {
        int kb = c * 32;
        bf16x8 af0 = *(const bf16x8*)(Ks + (kb + ln16) * 40 + quad * 8);
        bf16x8 af1 = *(const bf16x8*)(Ks + (kb + 16 + ln16) * 40 + quad * 8);
        f16x4 va[2][2];
        #pragma unroll
        for (int dt = 0; dt < 2; ++dt)
            #pragma unroll
            for (int kt = 0; kt < 2; ++kt)
                va[dt][kt] = *(const f16x4*)(Vt + (dt * 16 + ln16) * 328
                                             + kb + kt * 16 + quad * 4);
        ushort4 m4a = *(const ushort4*)(meta + kb + quad * 4);
        ushort4 m4b = *(const ushort4*)(meta + kb + 16 + quad * 4);
        u16 mta[4] = {m4a.x, m4a.y, m4a.z, m4a.w};
        u16 mtb[4] = {m4b.x, m4b.y, m4b.z, m4b.w};

        #pragma unroll
        for (int qt = 0; qt < 4; ++qt) {
            f32x4 s0 = __builtin_amdgcn_mfma_f32_16x16x32_bf16(af0, qf[qt], zero, 0, 0, 0);
            f32x4 s1 = __builtin_amdgcn_mfma_f32_16x16x32_bf16(af1, qf[qt], zero, 0, 0, 0);
            float p[8];
            #pragma unroll
            for (int r = 0; r < 4; ++r) {
                int ma = mta[r], mb = mtb[r];
                float va0 = fmaf(s0[r], QSCALE2, tbl[basen[qt] + (ma & 0xFF)]);
                float vb0 = fmaf(s1[r], QSCALE2, tbl[basen[qt] + (mb & 0xFF)]);
                p[r]     = va0 + (((ma >> 8) == myreg[qt]) ? 0.0f : MASK2);
                p[4 + r] = vb0 + (((mb >> 8) == myreg[qt]) ? 0.0f : MASK2);
            }
            float ls = 0.0f;
            #pragma unroll
            for (int j = 0; j < 8; ++j) { p[j] = ex2(p[j]); ls += p[j]; }
            l_[qt] += ls;
            uint2 pk0 = { pkh(p[0], p[1]), pkh(p[2], p[3]) };
            uint2 pk1 = { pkh(p[4], p[5]), pkh(p[6], p[7]) };
            f16x4 pf0 = __builtin_bit_cast(f16x4, pk0);
            f16x4 pf1 = __builtin_bit_cast(f16x4, pk1);
            #pragma unroll
            for (int dt = 0; dt < 2; ++dt) {
                o[qt][dt] = __builtin_amdgcn_mfma_f32_16x16x16f16(va[dt][0], pf0, o[qt][dt], 0, 0, 0);
                o[qt][dt] = __builtin_amdgcn_mfma_f32_16x16x16f16(va[dt][1], pf1, o[qt][dt], 0, 0, 0);
            }
        }
    }

    #pragma unroll
    for (int qt = 0; qt < 4; ++qt) {
        float lt = l_[qt];
        lt += __shfl_xor(lt, 16, 64);
        lt += __shfl_xor(lt, 32, 64);
        float inv = 1.0f / lt;
        int nq = wv * 64 + qt * 16 + ln16;
        u16* dst = attout + ((size_t)(b_ * NWIN + nq)) * DIM + head * HD + quad * 4;
        #pragma unroll
        for (int dt = 0; dt < 2; ++dt) {
            u32 w0 = (u32)f2bf(o[qt][dt][0] * inv) | ((u32)f2bf(o[qt][dt][1] * inv) << 16);
            u32 w1 = (u32)f2bf(o[qt][dt][2] * inv) | ((u32)f2bf(o[qt][dt][3] * inv) << 16);
            uint2 st = {w0, w1};
            *(uint2*)(dst + dt * 16) = st;
        }
    }
}

// ---------------------------------------------------------------------------
extern "C" void kernel_launch(void* const* d_in, const int* in_sizes, int n_in,
                              void* d_out, int out_size, void* d_ws, size_t ws_size,
                              hipStream_t stream)
{
    (void)in_sizes; (void)n_in; (void)out_size; (void)ws_size;
    const float* x      = (const float*)d_in[0];
    const float* ln1_g  = (const float*)d_in[1];
    const float* ln1_b  = (const float*)d_in[2];
    const float* qkv_w  = (const float*)d_in[3];
    const float* qkv_b  = (const float*)d_in[4];
    const float* table  = (const float*)d_in[5];
    const float* proj_w = (const float*)d_in[6];
    const float* proj_b = (const float*)d_in[7];
    const float* ln2_g  = (const float*)d_in[8];
    const float* ln2_b  = (const float*)d_in[9];
    const float* fc1_w  = (const float*)d_in[10];
    const float* fc1_b  = (const float*)d_in[11];
    const float* fc2_w  = (const float*)d_in[12];
    const float* fc2_b  = (const float*)d_in[13];
    float* out = (float*)d_out;

    u16* wsu     = (u16*)d_ws;
    u16* h_buf   = wsu;
    u16* qkv_buf = wsu + (size_t)MROWS * DIM;
    u16* att_buf = wsu + (size_t)MROWS * (4 * DIM);
    u16* wq = wsu + (size_t)MROWS * (5 * DIM);
    u16* wp = wq + 3 * DIM * DIM;
    u16* w1 = wp + DIM * DIM;
    u16* w2 = w1 + 4 * DIM * DIM;

    cvt4_kernel<<<(12 * DIM * DIM) / 256, 256, 0, stream>>>(
        qkv_w, proj_w, fc1_w, fc2_w, wq, wp, w1, w2);

    ln_kernel<<<MROWS / 4, 256, 0, stream>>>(x, ln1_g, ln1_b, h_buf);
    mfma_gemm<0, 128><<<dim3(3 * DIM / 64, MROWS / 128), 256, 0, stream>>>(
        h_buf, wq, qkv_b, qkv_buf, nullptr, 3 * DIM, DIM);
    attn_kernel<<<128 * HEADS, 320, 0, stream>>>(qkv_buf, table, att_buf);
    mfma_gemm<2, 64><<<dim3(DIM / 64, MROWS / 64), 256, 0, stream>>>(
        att_buf, wp, proj_b, out, x, DIM, DIM);
    ln_kernel<<<MROWS / 4, 256, 0, stream>>>(out, ln2_g, ln2_b, h_buf);
    fused_mlp<<<MROWS / 64, 256, 0, stream>>>(
        h_buf, w1, w2, fc1_b, fc2_b, out);
}

// Round 12
// 249.388 us; speedup vs baseline: 1.1396x; 1.1396x over previous
//
#include <hip/hip_runtime.h>
#include <math.h>

typedef unsigned short u16;
typedef unsigned int u32;
typedef short bf16x8 __attribute__((ext_vector_type(8)));
typedef float f32x4 __attribute__((ext_vector_type(4)));
typedef _Float16 f16x4 __attribute__((ext_vector_type(4)));

#define TT 5
#define HEADS 6
#define HD 32
#define DIM 192
#define NWIN 320              // tokens per window = T*8*8
#define LTOK (TT*64*64)       // 20480
#define BATCH 2
#define MROWS (BATCH*LTOK)    // 40960
#define QSCALE 0.17677669529663687f   // 1/sqrt(32)
#define LOG2E 1.4426950408889634f
#define QSCALE2 (QSCALE * LOG2E)
#define MASK2 (-100.0f * LOG2E)       // -144.2695: 2^x -> 0

__device__ __forceinline__ u16 f2bf(float f) {
    u32 u = __float_as_uint(f);
    u32 r = (u + 0x7FFFu + ((u >> 16) & 1u)) >> 16;
    return (u16)r;
}
__device__ __forceinline__ float bflo(u32 u) { return __uint_as_float(u << 16); }
__device__ __forceinline__ float bfhi(u32 u) { return __uint_as_float(u & 0xFFFF0000u); }
__device__ __forceinline__ u32 pkh(float a, float b) {
    auto h = __builtin_amdgcn_cvt_pkrtz(a, b);
    return __builtin_bit_cast(u32, h);
}
#if __has_builtin(__builtin_amdgcn_exp2f)
__device__ __forceinline__ float ex2(float x) { return __builtin_amdgcn_exp2f(x); }
#else
__device__ __forceinline__ float ex2(float x) {
    float r; asm("v_exp_f32 %0, %1" : "=v"(r) : "v"(x)); return r;
}
#endif

// ---------------- fp32 -> bf16 weight conversion (all 4 weights fused) ----
__global__ __launch_bounds__(256) void cvt4_kernel(
    const float* __restrict__ a, const float* __restrict__ b,
    const float* __restrict__ c, const float* __restrict__ d,
    u16* __restrict__ oa, u16* __restrict__ ob,
    u16* __restrict__ oc, u16* __restrict__ od)
{
    int i = blockIdx.x * 256 + threadIdx.x;
    if (i < 110592)       oa[i]          = f2bf(a[i]);            // qkv_w 3*DIM*DIM
    else if (i < 147456)  ob[i - 110592] = f2bf(b[i - 110592]);   // proj_w DIM*DIM
    else if (i < 294912)  oc[i - 147456] = f2bf(c[i - 147456]);   // fc1_w 4*DIM*DIM
    else                  od[i - 294912] = f2bf(d[i - 294912]);   // fc2_w 4*DIM*DIM
}

// ---------------- LayerNorm: one wave per token, bf16 output --------------
// (only LN1 now; LN2 fused into proj_ln_kernel epilogue)
__global__ __launch_bounds__(256) void ln_kernel(
    const float* __restrict__ x, const float* __restrict__ g,
    const float* __restrict__ b, u16* __restrict__ out)
{
    int tok  = blockIdx.x * 4 + (threadIdx.x >> 6);
    int lane = threadIdx.x & 63;
    const float* xr = x + (size_t)tok * DIM;
    float v0 = xr[lane], v1 = xr[lane + 64], v2 = xr[lane + 128];
    float s = v0 + v1 + v2;
    #pragma unroll
    for (int off = 32; off; off >>= 1) s += __shfl_xor(s, off, 64);
    float mu = s * (1.0f / 192.0f);
    float d0 = v0 - mu, d1 = v1 - mu, d2 = v2 - mu;
    float vs = d0 * d0 + d1 * d1 + d2 * d2;
    #pragma unroll
    for (int off = 32; off; off >>= 1) vs += __shfl_xor(vs, off, 64);
    float rstd = rsqrtf(vs * (1.0f / 192.0f) + 1e-5f);
    u16* orow = out + (size_t)tok * DIM;
    orow[lane]       = f2bf(d0 * rstd * g[lane]       + b[lane]);
    orow[lane + 64]  = f2bf(d1 * rstd * g[lane + 64]  + b[lane + 64]);
    orow[lane + 128] = f2bf(d2 * rstd * g[lane + 128] + b[lane + 128]);
}

// ---------------- bf16 MFMA GEMM: C = A(MxK) @ W(NxK)^T + bias ------------
// r4 structure (single-buffer staged loop + XCD swizzle). History: r5 dbuf /
// r7 direct-A / r8 hoist / r11 fused-MLP all regressed -- do not revisit.
// BM=64 for fc2 (grid fill); qkv/fc1 keep 128.
template<int EPI, int BM>
__global__ __launch_bounds__(256) void mfma_gemm(
    const u16* __restrict__ A, const u16* __restrict__ W,
    const float* __restrict__ bias, void* __restrict__ outp,
    const float* __restrict__ xin, int N, int K)
{
    constexpr int WR = BM / 64;     // 16-row tiles per wave
    constexpr int NA = BM / 32;     // A-stage chunks per K-step
    __shared__ u16 As[BM * 64];
    __shared__ u16 Bs[64 * 64];
    const int tid  = threadIdx.x;
    const int lane = tid & 63, wv = tid >> 6;
    const int ln16 = lane & 15, quad = lane >> 4;

    const int flat  = blockIdx.y * gridDim.x + blockIdx.x;
    const int cpx   = (gridDim.x * gridDim.y) >> 3;
    const int nf    = (flat & 7) * cpx + (flat >> 3);
    const int bn    = nf % gridDim.x;
    const int bm    = nf / gridDim.x;

    const int srow = lane >> 3;
    const int sxor = (lane & 7) ^ srow;
    const int acol = sxor * 8;

    f32x4 acc[WR][4] = {};

    for (int k0 = 0; k0 < K; k0 += 64) {
        __syncthreads();
        #pragma unroll
        for (int a = 0; a < NA; ++a) {
            const u16* g = A + (size_t)(bm * BM + a * 32 + wv * 8 + srow) * K + k0 + acol;
            __builtin_amdgcn_global_load_lds(
                (const __attribute__((address_space(1))) u32*)g,
                (__attribute__((address_space(3))) u32*)((char*)As + a * 4096 + wv * 1024),
                16, 0, 0);
        }
        #pragma unroll
        for (int bb = 0; bb < 2; ++bb) {
            const u16* g = W + (size_t)(bn * 64 + bb * 32 + wv * 8 + srow) * K + k0 + acol;
            __builtin_amdgcn_global_load_lds(
                (const __attribute__((address_space(1))) u32*)g,
                (__attribute__((address_space(3))) u32*)((char*)Bs + bb * 4096 + wv * 1024),
                16, 0, 0);
        }
        __syncthreads();
        #pragma unroll
        for (int s = 0; s < 2; ++s) {
            bf16x8 af[WR], bf[4];
            #pragma unroll
            for (int i = 0; i < WR; ++i) {
                int r = wv * (16 * WR) + i * 16 + ln16;
                int slot = (s * 4 + quad) ^ (r & 7);
                af[i] = *(const bf16x8*)((const char*)As + r * 128 + slot * 16);
            }
            #pragma unroll
            for (int j = 0; j < 4; ++j) {
                int r = j * 16 + ln16;
                int slot = (s * 4 + quad) ^ (r & 7);
                bf[j] = *(const bf16x8*)((const char*)Bs + r * 128 + slot * 16);
            }
            #pragma unroll
            for (int i = 0; i < WR; ++i)
                #pragma unroll
                for (int j = 0; j < 4; ++j)
                    acc[i][j] = __builtin_amdgcn_mfma_f32_16x16x32_bf16(
                        af[i], bf[j], acc[i][j], 0, 0, 0);
        }
    }

    #pragma unroll
    for (int i = 0; i < WR; ++i) {
        int gr0 = bm * BM + wv * (16 * WR) + i * 16 + quad * 4;
        #pragma unroll
        for (int j = 0; j < 4; ++j) {
            int gc = bn * 64 + j * 16 + ln16;
            float bv = bias[gc];
            #pragma unroll
            for (int rr = 0; rr < 4; ++rr) {
                int gr = gr0 + rr;
                float val = acc[i][j][rr] + bv;
                if (EPI == 0) {
                    ((u16*)outp)[(size_t)gr * N + gc] = f2bf(val);
                } else if (EPI == 1) {
                    float gl = val * 0.5f * (1.0f + erff(val * 0.70710678118654752f));
                    ((u16*)outp)[(size_t)gr * N + gc] = f2bf(gl);
                } else {
                    ((float*)outp)[(size_t)gr * N + gc] += val;
                }
            }
        }
    }
}

// ---- proj GEMM (full 192-col rows) + residual + FUSED LN2 epilogue -------
// BM=64, BN=192: one block owns complete rows, so after out = x + projval
// the 16 ln16-lanes of each (wave,quad) group hold an entire row ->
// row stats via 12-reg partials + 4 shfl_xor (single-pass E[x2]-E[x]2,
// error << bf16 tolerance). Writes out (f32 residual) AND h_buf (bf16 LN2)
// -- deletes the second ln_kernel dispatch and its 31.5MB re-read.
// LDS 32KB; all LDS reads are the proven conflict-free b128 slot pattern.
__global__ __launch_bounds__(256) void proj_ln_kernel(
    const u16* __restrict__ A,       // att_buf bf16 [MROWS][192]
    const u16* __restrict__ W,       // proj_w bf16 [192][192]
    const float* __restrict__ bias,  // proj_b
    const float* __restrict__ xin,   // x f32
    float* __restrict__ out,         // x + attnproj (f32)
    const float* __restrict__ g2, const float* __restrict__ b2,
    u16* __restrict__ hout)          // h_buf bf16 = LN2(out)
{
    __shared__ u16 As[64 * 64];      // 8KB
    __shared__ u16 Bs[192 * 64];     // 24KB
    const int tid  = threadIdx.x;
    const int lane = tid & 63, wv = tid >> 6;
    const int ln16 = lane & 15, quad = lane >> 4;
    const int srow = lane >> 3;
    const int acol = ((lane & 7) ^ srow) * 8;

    const int flat = blockIdx.x;                 // grid 640, %8==0
    const int bm   = (flat & 7) * (gridDim.x >> 3) + (flat >> 3);

    f32x4 acc[12] = {};

    for (int k0 = 0; k0 < DIM; k0 += 64) {
        __syncthreads();
        #pragma unroll
        for (int a = 0; a < 2; ++a) {
            const u16* g = A + (size_t)(bm * 64 + a * 32 + wv * 8 + srow) * DIM + k0 + acol;
            __builtin_amdgcn_global_load_lds(
                (const __attribute__((address_space(1))) u32*)g,
                (__attribute__((address_space(3))) u32*)((char*)As + a * 4096 + wv * 1024),
                16, 0, 0);
        }
        #pragma unroll
        for (int bb = 0; bb < 6; ++bb) {
            const u16* g = W + (size_t)(bb * 32 + wv * 8 + srow) * DIM + k0 + acol;
            __builtin_amdgcn_global_load_lds(
                (const __attribute__((address_space(1))) u32*)g,
                (__attribute__((address_space(3))) u32*)((char*)Bs + bb * 4096 + wv * 1024),
                16, 0, 0);
        }
        __syncthreads();
        #pragma unroll
        for (int s = 0; s < 2; ++s) {
            int ra = wv * 16 + ln16;
            int slota = (s * 4 + quad) ^ (ra & 7);
            bf16x8 af = *(const bf16x8*)((const char*)As + ra * 128 + slota * 16);
            #pragma unroll
            for (int nt = 0; nt < 12; ++nt) {
                int r = nt * 16 + ln16;
                int slot = (s * 4 + quad) ^ (r & 7);
                bf16x8 bf = *(const bf16x8*)((const char*)Bs + r * 128 + slot * 16);
                acc[nt] = __builtin_amdgcn_mfma_f32_16x16x32_bf16(af, bf, acc[nt], 0, 0, 0);
            }
        }
    }

    // ---- pass 1: residual add, store out, accumulate row stats -----------
    const int gr0 = bm * 64 + wv * 16 + quad * 4;
    float s1[4] = {}, s2[4] = {};
    #pragma unroll
    for (int nt = 0; nt < 12; ++nt) {
        int gc = nt * 16 + ln16;
        float bv = bias[gc];
        #pragma unroll
        for (int rr = 0; rr < 4; ++rr) {
            size_t dst = (size_t)(gr0 + rr) * DIM + gc;
            float ov = xin[dst] + acc[nt][rr] + bv;
            out[dst] = ov;
            s1[rr] += ov;
            s2[rr] += ov * ov;
        }
    }
    #pragma unroll
    for (int rr = 0; rr < 4; ++rr) {
        #pragma unroll
        for (int off = 8; off; off >>= 1) {
            s1[rr] += __shfl_xor(s1[rr], off, 64);
            s2[rr] += __shfl_xor(s2[rr], off, 64);
        }
    }
    float mu[4], rstd[4];
    #pragma unroll
    for (int rr = 0; rr < 4; ++rr) {
        mu[rr] = s1[rr] * (1.0f / 192.0f);
        float var = s2[rr] * (1.0f / 192.0f) - mu[rr] * mu[rr];
        rstd[rr] = rsqrtf(var + 1e-5f);
    }
    // ---- pass 2: LN2 -> h_buf (re-derive ov from acc; xin reload L2-hot) --
    #pragma unroll
    for (int nt = 0; nt < 12; ++nt) {
        int gc = nt * 16 + ln16;
        float bv = bias[gc];
        float gg = g2[gc], bb = b2[gc];
        #pragma unroll
        for (int rr = 0; rr < 4; ++rr) {
            size_t dst = (size_t)(gr0 + rr) * DIM + gc;
            float ov = xin[dst] + acc[nt][rr] + bv;
            hout[dst] = f2bf((ov - mu[rr]) * rstd[rr] * gg + bb);
        }
    }
}

// ---------------- MFMA flash attention: block = (window, head) ------------
// r4 version verbatim (41.6us, VGPR=60, static-max exp2 softmax,
// window-order store). VGPR must stay <= 64 (m69 cliff).
__global__ __launch_bounds__(320) void attn_kernel(
    const u16* __restrict__ qkv, const float* __restrict__ table,
    u16* __restrict__ attout)
{
    const int head = blockIdx.x % HEADS;
    const int b_   = blockIdx.x / HEADS;
    const int b = b_ >> 6, hb = (b_ >> 3) & 7, wb = b_ & 7;
    const int tid = threadIdx.x;
    const int lane = tid & 63, wv = tid >> 6;
    const int ln16 = lane & 15, quad = lane >> 4;

    __shared__ u16 Ks[320 * 40];     // bf16, row pad 40 (16B-aligned rows)
    __shared__ u16 Vt[32 * 328];     // f16 transposed, row pad 328
    __shared__ u16 meta[320];        // off | (region<<8) per key token
    __shared__ float tbl[188];       // bias table pre-scaled by log2(e)

    {
        int n = tid;
        int t1 = n >> 6, r1 = (n >> 3) & 7, c1 = n & 7;
        int h1 = hb * 8 + r1, w1 = wb * 8 + c1;
        int l1 = t1 * 4096 + ((h1 + 4) & 63) * 64 + ((w1 + 4) & 63);
        const u16* src = qkv + ((size_t)b * LTOK + l1) * (3 * DIM) + head * HD;
        const uint4* k4 = (const uint4*)(src + DIM);
        #pragma unroll
        for (int i = 0; i < 4; ++i)
            *(uint4*)(Ks + n * 40 + i * 8) = k4[i];
        const uint4* v4 = (const uint4*)(src + 2 * DIM);
        #pragma unroll
        for (int i = 0; i < 4; ++i) {
            uint4 u = v4[i];
            u32 ws[4] = {u.x, u.y, u.z, u.w};
            #pragma unroll
            for (int j = 0; j < 4; ++j) {
                u32 hb2 = pkh(bflo(ws[j]), bfhi(ws[j]));
                int d = i * 8 + j * 2;
                Vt[d * 328 + n]       = (u16)(hb2 & 0xFFFF);
                Vt[(d + 1) * 328 + n] = (u16)(hb2 >> 16);
            }
        }
        int off = (7 - t1) * 15 + 7 - r1 - c1;
        int rh = h1 < 56 ? 0 : (h1 < 60 ? 1 : 2);
        int rw = w1 < 56 ? 0 : (w1 < 60 ? 1 : 2);
        meta[n] = (u16)(off | ((rh * 3 + rw) << 8));
        if (n < 187) tbl[n] = table[n * HEADS + head] * LOG2E;
    }

    bf16x8 qf[4];
    int basen[4], myreg[4];
    #pragma unroll
    for (int qt = 0; qt < 4; ++qt) {
        int nq = wv * 64 + qt * 16 + ln16;
        int t1 = nq >> 6, r1 = (nq >> 3) & 7, c1 = nq & 7;
        int h1 = hb * 8 + r1, w1 = wb * 8 + c1;
        int l1 = t1 * 4096 + ((h1 + 4) & 63) * 64 + ((w1 + 4) & 63);
        qf[qt] = *(const bf16x8*)(qkv + ((size_t)b * LTOK + l1) * (3 * DIM)
                                  + head * HD + quad * 8);
        basen[qt] = t1 * 15 + r1 + c1;
        int rh = h1 < 56 ? 0 : (h1 < 60 ? 1 : 2);
        int rw = w1 < 56 ? 0 : (w1 < 60 ? 1 : 2);
        myreg[qt] = rh * 3 + rw;
    }

    __syncthreads();

    f32x4 o[4][2] = {};
    float l_[4] = {};
    const f32x4 zero = {};

    #pragma unroll 1
    for (int c = 0; c < 10; ++c) {
        int kb = c * 32;
        bf16x8 af0 = *(const bf16x8*)(Ks + (kb + ln16) * 40 + quad * 8);
        bf16x8 af1 = *(const bf16x8*)(Ks + (kb + 16 + ln16) * 40 + quad * 8);
        f16x4 va[2][2];
        #pragma unroll
        for (int dt = 0; dt < 2; ++dt)
            #pragma unroll
            for (int kt = 0; kt < 2; ++kt)
                va[dt][kt] = *(const f16x4*)(Vt + (dt * 16 + ln16) * 328
                                             + kb + kt * 16 + quad * 4);
        ushort4 m4a = *(const ushort4*)(meta + kb + quad * 4);
        ushort4 m4b = *(const ushort4*)(meta + kb + 16 + quad * 4);
        u16 mta[4] = {m4a.x, m4a.y, m4a.z, m4a.w};
        u16 mtb[4] = {m4b.x, m4b.y, m4b.z, m4b.w};

        #pragma unroll
        for (int qt = 0; qt < 4; ++qt) {
            f32x4 s0 = __builtin_amdgcn_mfma_f32_16x16x32_bf16(af0, qf[qt], zero, 0, 0, 0);
            f32x4 s1 = __builtin_amdgcn_mfma_f32_16x16x32_bf16(af1, qf[qt], zero, 0, 0, 0);
            float p[8];
            #pragma unroll
            for (int r = 0; r < 4; ++r) {
                int ma = mta[r], mb = mtb[r];
                float va0 = fmaf(s0[r], QSCALE2, tbl[basen[qt] + (ma & 0xFF)]);
                float vb0 = fmaf(s1[r], QSCALE2, tbl[basen[qt] + (mb & 0xFF)]);
                p[r]     = va0 + (((ma >> 8) == myreg[qt]) ? 0.0f : MASK2);
                p[4 + r] = vb0 + (((mb >> 8) == myreg[qt]) ? 0.0f : MASK2);
            }
            float ls = 0.0f;
            #pragma unroll
            for (int j = 0; j < 8; ++j) { p[j] = ex2(p[j]); ls += p[j]; }
            l_[qt] += ls;
            uint2 pk0 = { pkh(p[0], p[1]), pkh(p[2], p[3]) };
            uint2 pk1 = { pkh(p[4], p[5]), pkh(p[6], p[7]) };
            f16x4 pf0 = __builtin_bit_cast(f16x4, pk0);
            f16x4 pf1 = __builtin_bit_cast(f16x4, pk1);
            #pragma unroll
            for (int dt = 0; dt < 2; ++dt) {
                o[qt][dt] = __builtin_amdgcn_mfma_f32_16x16x16f16(va[dt][0], pf0, o[qt][dt], 0, 0, 0);
                o[qt][dt] = __builtin_amdgcn_mfma_f32_16x16x16f16(va[dt][1], pf1, o[qt][dt], 0, 0, 0);
            }
        }
    }

    #pragma unroll
    for (int qt = 0; qt < 4; ++qt) {
        float lt = l_[qt];
        lt += __shfl_xor(lt, 16, 64);
        lt += __shfl_xor(lt, 32, 64);
        float inv = 1.0f / lt;
        int nq = wv * 64 + qt * 16 + ln16;
        u16* dst = attout + ((size_t)(b_ * NWIN + nq)) * DIM + head * HD + quad * 4;
        #pragma unroll
        for (int dt = 0; dt < 2; ++dt) {
            u32 w0 = (u32)f2bf(o[qt][dt][0] * inv) | ((u32)f2bf(o[qt][dt][1] * inv) << 16);
            u32 w1 = (u32)f2bf(o[qt][dt][2] * inv) | ((u32)f2bf(o[qt][dt][3] * inv) << 16);
            uint2 st = {w0, w1};
            *(uint2*)(dst + dt * 16) = st;
        }
    }
}

// ---------------------------------------------------------------------------
extern "C" void kernel_launch(void* const* d_in, const int* in_sizes, int n_in,
                              void* d_out, int out_size, void* d_ws, size_t ws_size,
                              hipStream_t stream)
{
    (void)in_sizes; (void)n_in; (void)out_size; (void)ws_size;
    const float* x      = (const float*)d_in[0];
    const float* ln1_g  = (const float*)d_in[1];
    const float* ln1_b  = (const float*)d_in[2];
    const float* qkv_w  = (const float*)d_in[3];
    const float* qkv_b  = (const float*)d_in[4];
    const float* table  = (const float*)d_in[5];
    const float* proj_w = (const float*)d_in[6];
    const float* proj_b = (const float*)d_in[7];
    const float* ln2_g  = (const float*)d_in[8];
    const float* ln2_b  = (const float*)d_in[9];
    const float* fc1_w  = (const float*)d_in[10];
    const float* fc1_b  = (const float*)d_in[11];
    const float* fc2_w  = (const float*)d_in[12];
    const float* fc2_b  = (const float*)d_in[13];
    float* out = (float*)d_out;

    u16* wsu     = (u16*)d_ws;
    u16* h_buf   = wsu;
    u16* qkv_buf = wsu + (size_t)MROWS * DIM;
    u16* att_buf = wsu + (size_t)MROWS * (4 * DIM);
    u16* fc1_buf = wsu + (size_t)MROWS * DIM;
    u16* wq = wsu + (size_t)MROWS * (5 * DIM);
    u16* wp = wq + 3 * DIM * DIM;
    u16* w1 = wp + DIM * DIM;
    u16* w2 = w1 + 4 * DIM * DIM;

    cvt4_kernel<<<(12 * DIM * DIM) / 256, 256, 0, stream>>>(
        qkv_w, proj_w, fc1_w, fc2_w, wq, wp, w1, w2);

    ln_kernel<<<MROWS / 4, 256, 0, stream>>>(x, ln1_g, ln1_b, h_buf);
    mfma_gemm<0, 128><<<dim3(3 * DIM / 64, MROWS / 128), 256, 0, stream>>>(
        h_buf, wq, qkv_b, qkv_buf, nullptr, 3 * DIM, DIM);
    attn_kernel<<<128 * HEADS, 320, 0, stream>>>(qkv_buf, table, att_buf);
    proj_ln_kernel<<<MROWS / 64, 256, 0, stream>>>(
        att_buf, wp, proj_b, x, out, ln2_g, ln2_b, h_buf);
    mfma_gemm<1, 128><<<dim3(4 * DIM / 64, MROWS / 128), 256, 0, stream>>>(
        h_buf, w1, fc1_b, fc1_buf, nullptr, 4 * DIM, DIM);
    mfma_gemm<3, 64><<<dim3(DIM / 64, MROWS / 64), 256, 0, stream>>>(
        fc1_buf, w2, fc2_b, out, nullptr, DIM, 4 * DIM);
}